// Round 1
// baseline (448.929 us; speedup 1.0000x reference)
//
#include <hip/hip_runtime.h>
#include <cmath>

#define NB 16
#define NL 64
#define NP 512
#define NH 128
#define NG 10
#define ROWS (NB * NL * NP)          // 524288 = rows of Interact

// output layout (flat float32, reference return order)
#define OFF_PI    ((size_t)0)
#define OFF_SIGMA ((size_t)5242880)
#define OFF_MU    ((size_t)10485760)
#define OFF_DIST  ((size_t)15728640)
#define OFF_MASK  ((size_t)16252928)

// ---------------------------------------------------------------------------
// Kernel 1: min-distance over 24 atoms + mask application + mask-as-float out
// one thread per (b, l, p)
// ---------------------------------------------------------------------------
__global__ __launch_bounds__(256) void k_dist(
    const float* __restrict__ pos_l,   // [B, NL, 3]
    const float* __restrict__ pos_p,   // [B, NP, 24, 3]
    const int*   __restrict__ mask,    // [B, NL, NP] (bool as int32)
    float* __restrict__ dist_out,      // [B, NL, NP]
    float* __restrict__ mask_out)      // [B, NL, NP]
{
    int idx = blockIdx.x * 256 + threadIdx.x;   // b*NL*NP + l*NP + p
    int p  = idx & (NP - 1);
    int bl = idx >> 9;                          // b*NL + l
    int b  = bl >> 6;

    const float* xl = pos_l + bl * 3;
    float x0 = xl[0], x1 = xl[1], x2 = xl[2];
    float xs = x0 * x0 + x1 * x1 + x2 * x2;

    // 24 atoms * 3 floats = 72 floats = 18 float4, 16B-aligned (72*4=288B rows)
    const float4* yp = (const float4*)(pos_p + ((size_t)(b * NP + p)) * 72);

    float m = 1e30f;
    #pragma unroll
    for (int q = 0; q < 6; ++q) {               // 4 atoms per iteration
        float4 v0 = yp[q * 3 + 0];
        float4 v1 = yp[q * 3 + 1];
        float4 v2 = yp[q * 3 + 2];
        float c[12] = {v0.x, v0.y, v0.z, v0.w,
                       v1.x, v1.y, v1.z, v1.w,
                       v2.x, v2.y, v2.z, v2.w};
        #pragma unroll
        for (int a = 0; a < 4; ++a) {
            float yx = c[a * 3 + 0], yy = c[a * 3 + 1], yz = c[a * 3 + 2];
            // same expanded formula as the reference: |x|^2 + |y|^2 - 2 x.y
            float d2 = xs + (yx * yx + yy * yy + yz * yz)
                          - 2.0f * (x0 * yx + x1 * yy + x2 * yz);
            // jnp.nan_to_num(sqrt(d2), nan=10000): d2<0 -> NaN -> 10000
            float s = (d2 >= 0.0f) ? sqrtf(d2) : 10000.0f;
            m = fminf(m, s);
        }
    }

    int mk = mask[idx];
    dist_out[idx] = mk ? m : 0.0f;
    mask_out[idx] = mk ? 1.0f : 0.0f;
}

// ---------------------------------------------------------------------------
// Kernel 2: fused 3x GEMV [128 -> 10] + softmax / leaky+clip / leaky
// one thread per row; W_pi|W_sigma|W_mu packed as [128][32] in LDS (pad 30->32)
// ---------------------------------------------------------------------------
__global__ __launch_bounds__(256) void k_gemv(
    const float* __restrict__ X,       // [ROWS, 128]
    const float* __restrict__ Wpi, const float* __restrict__ bpi,
    const float* __restrict__ Wsg, const float* __restrict__ bsg,
    const float* __restrict__ Wmu, const float* __restrict__ bmu,
    float* __restrict__ out_pi,
    float* __restrict__ out_sg,
    float* __restrict__ out_mu)
{
    __shared__ float lw[NH * 32];
    __shared__ float lb[32];
    int tid = threadIdx.x;

    for (int i = tid; i < NH * 32; i += 256) {
        int k = i >> 5, g = i & 31;
        float v = 0.0f;
        if      (g < 10) v = Wpi[k * NG + g];
        else if (g < 20) v = Wsg[k * NG + (g - 10)];
        else if (g < 30) v = Wmu[k * NG + (g - 20)];
        lw[i] = v;
    }
    if (tid < 32) {
        float v = 0.0f;
        if      (tid < 10) v = bpi[tid];
        else if (tid < 20) v = bsg[tid - 10];
        else if (tid < 30) v = bmu[tid - 20];
        lb[tid] = v;
    }
    __syncthreads();

    int row = blockIdx.x * 256 + tid;
    const float4* xr  = (const float4*)(X + (size_t)row * NH);
    const float4* lw4 = (const float4*)lw;

    float4 acc[8];
    #pragma unroll
    for (int g4 = 0; g4 < 8; ++g4) acc[g4] = ((const float4*)lb)[g4];

    #pragma unroll 4
    for (int k4 = 0; k4 < 32; ++k4) {
        float4 h = xr[k4];
        float hk[4] = {h.x, h.y, h.z, h.w};
        #pragma unroll
        for (int kk = 0; kk < 4; ++kk) {
            const float4* wrow = lw4 + (size_t)(k4 * 4 + kk) * 8;  // wave-uniform -> LDS broadcast
            float hv = hk[kk];
            #pragma unroll
            for (int g4 = 0; g4 < 8; ++g4) {
                float4 w = wrow[g4];
                acc[g4].x = fmaf(hv, w.x, acc[g4].x);
                acc[g4].y = fmaf(hv, w.y, acc[g4].y);
                acc[g4].z = fmaf(hv, w.z, acc[g4].z);
                acc[g4].w = fmaf(hv, w.w, acc[g4].w);
            }
        }
    }

    float a[32];
    #pragma unroll
    for (int g4 = 0; g4 < 8; ++g4) {
        a[g4 * 4 + 0] = acc[g4].x; a[g4 * 4 + 1] = acc[g4].y;
        a[g4 * 4 + 2] = acc[g4].z; a[g4 * 4 + 3] = acc[g4].w;
    }

    size_t ro = (size_t)row * NG;

    // pi = softmax(a[0..9])
    float mx = a[0];
    #pragma unroll
    for (int g = 1; g < NG; ++g) mx = fmaxf(mx, a[g]);
    float e[NG], s = 0.0f;
    #pragma unroll
    for (int g = 0; g < NG; ++g) { e[g] = __expf(a[g] - mx); s += e[g]; }
    float inv = 1.0f / s;
    #pragma unroll
    for (int g = 0; g < NG; ++g) out_pi[ro + g] = e[g] * inv;

    // sigma = clip(leaky(a[10..19]) + 1.1, 1e-6, inf)
    #pragma unroll
    for (int g = 0; g < NG; ++g) {
        float x = a[10 + g];
        float v = (x >= 0.0f ? x : 0.01f * x) + 1.1f;
        out_sg[ro + g] = fmaxf(v, 1e-6f);
    }

    // mu = leaky(a[20..29]) + 1.0
    #pragma unroll
    for (int g = 0; g < NG; ++g) {
        float x = a[20 + g];
        out_mu[ro + g] = (x >= 0.0f ? x : 0.01f * x) + 1.0f;
    }
}

// ---------------------------------------------------------------------------
extern "C" void kernel_launch(void* const* d_in, const int* in_sizes, int n_in,
                              void* d_out, int out_size, void* d_ws, size_t ws_size,
                              hipStream_t stream) {
    const float* pos_l    = (const float*)d_in[0];
    const float* pos_p    = (const float*)d_in[1];
    const float* Interact = (const float*)d_in[2];
    const int*   mask     = (const int*)  d_in[3];
    const float* Wpi      = (const float*)d_in[4];
    const float* bpi      = (const float*)d_in[5];
    const float* Wsg      = (const float*)d_in[6];
    const float* bsg      = (const float*)d_in[7];
    const float* Wmu      = (const float*)d_in[8];
    const float* bmu      = (const float*)d_in[9];

    float* out      = (float*)d_out;
    float* out_pi   = out + OFF_PI;
    float* out_sg   = out + OFF_SIGMA;
    float* out_mu   = out + OFF_MU;
    float* out_dist = out + OFF_DIST;
    float* out_mask = out + OFF_MASK;

    hipLaunchKernelGGL(k_dist, dim3(ROWS / 256), dim3(256), 0, stream,
                       pos_l, pos_p, mask, out_dist, out_mask);
    hipLaunchKernelGGL(k_gemv, dim3(ROWS / 256), dim3(256), 0, stream,
                       Interact, Wpi, bpi, Wsg, bsg, Wmu, bmu,
                       out_pi, out_sg, out_mu);
}